// Round 1
// baseline (8655.881 us; speedup 1.0000x reference)
//
#include <hip/hip_runtime.h>
#include <math.h>

#define T_ 64
#define B_ 256
#define N_ 256
#define M_ 128
#define H_ 1024
#define I_ 128
#define NB 256
#define NT 512
#define MSTR 132          // mem row stride (floats): 16B-aligned rows, bank-spread
#define EPSF 1e-8f

// ---- workspace layout (float offsets) ----
#define WS_RD   0                         // [B][M]
#define WS_HT   (WS_RD + B_*M_)           // [B][H]
#define WS_PROJ (WS_HT + B_*H_)           // [B][512]  k0|k1|erase|add (pre-activation, no bias)
#define WS_WCT  (WS_PROJ + B_*512)        // [H][256]  Wc transposed
#define WS_W2T  (WS_WCT + H_*256)         // [512][H]  packed head/erase/add weights, c-major
#define WS_WSM  (WS_W2T + 512*H_)         // [12][H]   small-col weights (beta,g,gamma,shift)
#define WS_BAR  (WS_WSM + 12*H_)          // barrier uints (2048 B)

__device__ __forceinline__ float wave_rsum(float v) {
#pragma unroll
  for (int o = 32; o > 0; o >>= 1) v += __shfl_xor(v, o, 64);
  return v;
}
__device__ __forceinline__ float wave_rmax(float v) {
#pragma unroll
  for (int o = 32; o > 0; o >>= 1) v = fmaxf(v, __shfl_xor(v, o, 64));
  return v;
}

// two-level grid barrier, device(agent)-scope atomics (wbl2/inv for cross-XCD)
__device__ __forceinline__ void gridbar(unsigned* bar) {
  __syncthreads();
  if (threadIdx.x == 0) {
    unsigned* gen = bar + 272;
    unsigned g = __hip_atomic_load(gen, __ATOMIC_RELAXED, __HIP_MEMORY_SCOPE_AGENT);
    unsigned* leaf = bar + (blockIdx.x & 15) * 16;   // 64B-spaced leaves
    unsigned o = __hip_atomic_fetch_add(leaf, 1u, __ATOMIC_ACQ_REL, __HIP_MEMORY_SCOPE_AGENT);
    bool done = false;
    if (o == 15u) {
      __hip_atomic_store(leaf, 0u, __ATOMIC_RELAXED, __HIP_MEMORY_SCOPE_AGENT);
      unsigned r = __hip_atomic_fetch_add(bar + 256, 1u, __ATOMIC_ACQ_REL, __HIP_MEMORY_SCOPE_AGENT);
      if (r == 15u) {
        __hip_atomic_store(bar + 256, 0u, __ATOMIC_RELAXED, __HIP_MEMORY_SCOPE_AGENT);
        __hip_atomic_fetch_add(gen, 1u, __ATOMIC_RELEASE, __HIP_MEMORY_SCOPE_AGENT);
        done = true;
      }
    }
    if (!done) {
      while (__hip_atomic_load(gen, __ATOMIC_RELAXED, __HIP_MEMORY_SCOPE_AGENT) == g)
        __builtin_amdgcn_s_sleep(1);
      __builtin_amdgcn_fence(__ATOMIC_ACQUIRE, "agent");
    }
  }
  __syncthreads();
}

__global__ __launch_bounds__(NT)
void ntm_kernel(const float* __restrict__ x,   const float* __restrict__ Wc,  const float* __restrict__ bc,
                const float* __restrict__ Wk,  const float* __restrict__ bk,
                const float* __restrict__ Wb,  const float* __restrict__ bbv,
                const float* __restrict__ Wg,  const float* __restrict__ bg,
                const float* __restrict__ Wsf, const float* __restrict__ bsf,
                const float* __restrict__ Wgm, const float* __restrict__ bgm,
                const float* __restrict__ We,  const float* __restrict__ be,
                const float* __restrict__ Wa,  const float* __restrict__ ba,
                const float* __restrict__ Wo,  const float* __restrict__ bo,
                const float* __restrict__ mem0, const float* __restrict__ ww0,
                const float* __restrict__ rw0,  const float* __restrict__ rd0,
                float* __restrict__ out, float* __restrict__ ws)
{
  // persistent per-batch state in LDS (block b <-> batch b)
  __shared__ __align__(16) float mem[N_*MSTR];   // 135168 B
  __shared__ __align__(16) float prevw[2*N_];    // ww | rw
  __shared__ __align__(16) float mnv[N_];        // row norms (clamped)
  __shared__ __align__(16) float ksh[2*M_];      // k0 | k1
  __shared__ __align__(16) float eah[2*M_];      // erase | add
  __shared__ __align__(16) float hts[H_];
  __shared__ __align__(16) float wlog[2*N_];
  __shared__ __align__(16) float wtmp[2*N_];
  __shared__ __align__(16) float red[2*N_];
  __shared__ __align__(16) float scal[32];
  __shared__ __align__(16) float big[2048];      // staging scratch (8KB)

  const int tid = threadIdx.x;
  const int blk = blockIdx.x;
  unsigned* bar = (unsigned*)(ws + WS_BAR);
  float* rdws = ws + WS_RD;
  float* ht   = ws + WS_HT;
  float* proj = ws + WS_PROJ;
  float* WcT  = ws + WS_WCT;
  float* W2T  = ws + WS_W2T;
  float* Wsm  = ws + WS_WSM;

  // ================= prologue =================
  // WcT[h][k] = Wc[k][h]
  for (int i = blk*NT + tid; i < H_*256; i += NB*NT) {
    int h = i >> 8, k = i & 255;
    WcT[i] = Wc[k*H_ + h];
  }
  // W2T[c][k]: c<128 Wk0 | <256 Wk1 | <384 We | <512 Wa
  for (int i = blk*NT + tid; i < 512*H_; i += NB*NT) {
    int c = i >> 10, k = i & 1023;
    float v;
    if (c < 128)      v = Wk[k*M_ + c];
    else if (c < 256) v = Wk[H_*M_ + k*M_ + (c-128)];
    else if (c < 384) v = We[k*M_ + (c-256)];
    else              v = Wa[k*M_ + (c-384)];
    W2T[i] = v;
  }
  // Wsm[d][k]: 0,1 beta | 2,3 g | 4,5 gamma | 6-8 shift h0 | 9-11 shift h1
  for (int i = blk*NT + tid; i < 12*H_; i += NB*NT) {
    int d = i >> 10, k = i & 1023;
    float v;
    if (d < 2)      v = Wb[d*H_ + k];
    else if (d < 4) v = Wg[(d-2)*H_ + k];
    else if (d < 6) v = Wgm[(d-4)*H_ + k];
    else if (d < 9) v = Wsf[k*3 + (d-6)];
    else            v = Wsf[3*H_ + k*3 + (d-9)];
    Wsm[i] = v;
  }
  // initial rd
  if (tid < M_) rdws[blk*M_ + tid] = rd0[tid];
  // memory0 -> LDS
  for (int i = tid; i < N_*M_; i += NT) {
    int n = i >> 7, m = i & 127;
    mem[n*MSTR + m] = mem0[i];
  }
  __syncthreads();
  if (tid < N_) {
    float s = 0.f;
#pragma unroll 8
    for (int m = 0; m < M_; ++m) { float v = mem[tid*MSTR + m]; s += v*v; }
    mnv[tid] = fmaxf(sqrtf(s), EPSF);
  }
  if (tid < N_) { wlog[tid] = ww0[tid]; wlog[N_ + tid] = rw0[tid]; }
  __syncthreads();
  { // softmax(ww0), softmax(rw0)
    int wv = tid >> 6, ln = tid & 63;
    if (wv < 2) {
      float l0=wlog[wv*N_+ln], l1=wlog[wv*N_+64+ln], l2=wlog[wv*N_+128+ln], l3=wlog[wv*N_+192+ln];
      float mx = wave_rmax(fmaxf(fmaxf(l0,l1), fmaxf(l2,l3)));
      float e0=__expf(l0-mx), e1=__expf(l1-mx), e2=__expf(l2-mx), e3=__expf(l3-mx);
      float sm = wave_rsum(e0+e1+e2+e3);
      wlog[wv*N_+ln]=e0; wlog[wv*N_+64+ln]=e1; wlog[wv*N_+128+ln]=e2; wlog[wv*N_+192+ln]=e3;
      if (ln == 0) scal[30+wv] = 1.f/sm;
    }
  }
  __syncthreads();
  prevw[tid] = wlog[tid] * scal[30 + (tid >> 8)];
  gridbar(bar);

  // ================= time loop =================
  for (int t = 0; t < T_; ++t) {
    // ---- phase 1: ht = tanh([x_t, rd] @ Wc + bc) ; block=(btile, htile) ----
    {
      const int bt = blk >> 4, htl = blk & 15;
      const int hp = tid & 31, b_l = tid >> 5;          // 32 h-pairs x 16 b
      const int h0 = htl*64 + hp*2;
      float acc0 = 0.f, acc1 = 0.f;
      for (int kc = 0; kc < 2; ++kc) {
        __syncthreads();
        { // stage X2 chunk [16][128]
          const int bs = tid >> 5, k4 = tid & 31;
          float4 v = (kc == 0)
            ? *(const float4*)&x[((size_t)t*B_ + bt*16 + bs)*I_ + k4*4]
            : *(const float4*)&rdws[(bt*16 + bs)*M_ + k4*4];
          *(float4*)&big[bs*128 + k4*4] = v;
        }
        __syncthreads();
        const float4* w0 = (const float4*)&WcT[(size_t)h0*256 + kc*128];
        const float4* w1 = (const float4*)&WcT[(size_t)(h0+1)*256 + kc*128];
        const float4* xr = (const float4*)&big[b_l*128];
#pragma unroll 8
        for (int k4 = 0; k4 < 32; ++k4) {
          float4 a = w0[k4], b = w1[k4], c = xr[k4];
          acc0 += a.x*c.x + a.y*c.y + a.z*c.z + a.w*c.w;
          acc1 += b.x*c.x + b.y*c.y + b.z*c.z + b.w*c.w;
        }
      }
      int b = bt*16 + b_l;
      float2 o2;
      o2.x = tanhf(acc0 + bc[h0]);
      o2.y = tanhf(acc1 + bc[h0+1]);
      *(float2*)&ht[(size_t)b*H_ + h0] = o2;
    }
    gridbar(bar);

    // ---- phase 2: proj = ht @ W2 ; block=(btile, ctile) ----
    {
      const int bt = blk >> 4, ctl = blk & 15;
      const int c_l = tid & 31, b_l = tid >> 5;
      const int c = ctl*32 + c_l;
      const int b = bt*16 + b_l;
      float acc = 0.f;
      for (int kc = 0; kc < 8; ++kc) {
        __syncthreads();
        { // stage ht chunk [16][128]
          const int bs = tid >> 5, k4 = tid & 31;
          *(float4*)&big[bs*128 + k4*4] =
            *(const float4*)&ht[(size_t)(bt*16 + bs)*H_ + kc*128 + k4*4];
        }
        __syncthreads();
        const float4* wp = (const float4*)&W2T[(size_t)c*H_ + kc*128];
        const float4* hp4 = (const float4*)&big[b_l*128];
#pragma unroll 8
        for (int k4 = 0; k4 < 32; ++k4) {
          float4 w = wp[k4], h4 = hp4[k4];
          acc += w.x*h4.x + w.y*h4.y + w.z*h4.z + w.w*h4.w;
        }
      }
      proj[(size_t)b*512 + c] = acc;
    }
    gridbar(bar);

    // ---- phase 3: per-batch addressing + memory update + read (block b) ----
    {
      const int b = blk;
      { // activations of big projections + stage ht row
        float v = proj[(size_t)b*512 + tid];
        if (tid < 256)      ksh[tid] = fmaxf(v + bk[tid], 0.f);                 // k0|k1 relu
        else if (tid < 384) eah[tid-256] = 1.f/(1.f + __expf(-(v + be[tid-256])));   // erase
        else                eah[tid-256] = 1.f/(1.f + __expf(-(v + ba[tid-384])));   // add
        hts[tid]       = ht[(size_t)b*H_ + tid];
        hts[512 + tid] = ht[(size_t)b*H_ + 512 + tid];
      }
      __syncthreads();
      { // 12 small dots (waves 0-5) + k norms (waves 6-7)
        int wv = tid >> 6, ln = tid & 63;
        if (wv < 6) {
          for (int dd = 0; dd < 2; ++dd) {
            int d = wv*2 + dd;
            const float* wp = &Wsm[(size_t)d*H_];
            float s = 0.f;
#pragma unroll
            for (int j = 0; j < 16; ++j) s += hts[j*64 + ln] * wp[j*64 + ln];
            s = wave_rsum(s);
            if (ln == 0) scal[d] = s;
          }
        } else {
          int h = wv - 6;
          float s = 0.f;
          float v0 = ksh[h*128 + ln], v1 = ksh[h*128 + 64 + ln];
          s = v0*v0 + v1*v1;
          s = wave_rsum(s);
          if (ln == 0) scal[12 + h] = fmaxf(sqrtf(s), EPSF);
        }
      }
      __syncthreads();
      if (tid == 0) { // finalize scalars
        for (int h = 0; h < 2; ++h) {
          float rb = scal[h] + bbv[h];
          scal[16+h] = (rb > 20.f) ? rb : log1pf(__expf(rb));       // beta softplus
          scal[18+h] = 1.f/(1.f + __expf(-(scal[2+h] + bg[h])));    // g sigmoid
          scal[20+h] = fmaxf(scal[4+h] + bgm[h], 0.f) + 1.f;        // gamma
          float s0 = scal[6+3*h] + bsf[3*h+0];
          float s1 = scal[7+3*h] + bsf[3*h+1];
          float s2 = scal[8+3*h] + bsf[3*h+2];
          float mx = fmaxf(s0, fmaxf(s1, s2));
          float e0 = __expf(s0-mx), e1 = __expf(s1-mx), e2 = __expf(s2-mx);
          float inv = 1.f/(e0+e1+e2);
          scal[22+3*h] = e0*inv; scal[23+3*h] = e1*inv; scal[24+3*h] = e2*inv;
        }
      }
      __syncthreads();
      { // cosine logits: wave -> (head, 64 rows)
        int wv = tid >> 6, ln = tid & 63;
        int h = wv & 1, n = (wv >> 1)*64 + ln;
        const float beta = scal[16+h], kn = scal[12+h];
        const float4* kp = (const float4*)&ksh[h*128];
        const float* mrow = &mem[n*MSTR];
        float dot = 0.f;
#pragma unroll 8
        for (int m4 = 0; m4 < 32; ++m4) {
          float4 kv = kp[m4];
          float4 mv = *(const float4*)&mrow[m4*4];
          dot += kv.x*mv.x + kv.y*mv.y + kv.z*mv.z + kv.w*mv.w;
        }
        wlog[h*N_ + n] = beta * (dot / (kn * mnv[n]));
      }
      __syncthreads();
      { // content softmax (waves 0,1); exp written back, inv-sum -> scal[30+h]
        int wv = tid >> 6, ln = tid & 63;
        if (wv < 2) {
          float l0=wlog[wv*N_+ln], l1=wlog[wv*N_+64+ln], l2=wlog[wv*N_+128+ln], l3=wlog[wv*N_+192+ln];
          float mx = wave_rmax(fmaxf(fmaxf(l0,l1), fmaxf(l2,l3)));
          float e0=__expf(l0-mx), e1=__expf(l1-mx), e2=__expf(l2-mx), e3=__expf(l3-mx);
          float sm = wave_rsum(e0+e1+e2+e3);
          wlog[wv*N_+ln]=e0; wlog[wv*N_+64+ln]=e1; wlog[wv*N_+128+ln]=e2; wlog[wv*N_+192+ln]=e3;
          if (ln == 0) scal[30+wv] = 1.f/sm;
        }
      }
      __syncthreads();
      { // interpolate with previous weights
        int h = tid >> 8;
        float g = scal[18+h];
        wtmp[tid] = g * wlog[tid] * scal[30+h] + (1.f - g) * prevw[tid];
      }
      __syncthreads();
      { // circular shift + sharpen
        int h = tid >> 8, n = tid & 255;
        float v = scal[22+3*h] * wtmp[h*N_ + ((n+255)&255)]
                + scal[23+3*h] * wtmp[h*N_ + n]
                + scal[24+3*h] * wtmp[h*N_ + ((n+1)&255)];
        wlog[tid] = __powf(v, scal[20+h]);
      }
      __syncthreads();
      { // normalization sums
        int wv = tid >> 6, ln = tid & 63;
        if (wv < 2) {
          float s = wlog[wv*N_+ln] + wlog[wv*N_+64+ln] + wlog[wv*N_+128+ln] + wlog[wv*N_+192+ln];
          s = wave_rsum(s);
          if (ln == 0) scal[14+wv] = 1.f/s;
        }
      }
      __syncthreads();
      prevw[tid] = wlog[tid] * scal[14 + (tid >> 8)];
      __syncthreads();
      { // memory update + row-norm partials
        int n = tid & 255, half = tid >> 8;
        float wwn = prevw[n];
        float* mrow = &mem[n*MSTR + half*64];
        const float4* ep = (const float4*)&eah[half*64];
        const float4* ap = (const float4*)&eah[128 + half*64];
        float sq = 0.f;
#pragma unroll 4
        for (int m4 = 0; m4 < 16; ++m4) {
          float4 mv = *(float4*)&mrow[m4*4];
          float4 ev = ep[m4], av = ap[m4];
          mv.x = mv.x*(1.f - wwn*ev.x) + wwn*av.x;
          mv.y = mv.y*(1.f - wwn*ev.y) + wwn*av.y;
          mv.z = mv.z*(1.f - wwn*ev.z) + wwn*av.z;
          mv.w = mv.w*(1.f - wwn*ev.w) + wwn*av.w;
          sq += mv.x*mv.x + mv.y*mv.y + mv.z*mv.z + mv.w*mv.w;
          *(float4*)&mrow[m4*4] = mv;
        }
        red[half*N_ + n] = sq;
      }
      __syncthreads();
      if (tid < N_) mnv[tid] = fmaxf(sqrtf(red[tid] + red[N_+tid]), EPSF);
      __syncthreads();
      { // rd = rw @ mem_new (partials over 4 n-groups)
        int m = tid & 127, g = tid >> 7;
        float acc = 0.f;
        const float* base = &mem[(g*64)*MSTR + m];
#pragma unroll 4
        for (int i = 0; i < 64; ++i)
          acc += prevw[N_ + g*64 + i] * base[i*MSTR];
        red[g*128 + m] = acc;
      }
      __syncthreads();
      if (tid < M_) {
        float v = red[tid] + red[128+tid] + red[256+tid] + red[384+tid];
        rdws[blk*M_ + tid] = v;
        out[((size_t)t*B_ + blk)*I_ + tid] = v;   // stash rd; epilogue applies Wo
      }
    }
    gridbar(bar);
  }

  // ================= epilogue: out = rd @ Wo + bo (in place) =================
  for (int rr = 0; rr < 4; ++rr) {
    int r0 = blk*64 + rr*16;
    __syncthreads();
    { // stage 16 rd rows
      int rg = tid >> 5, c4 = tid & 31;
      *(float4*)&big[rg*128 + c4*4] = *(const float4*)&out[(size_t)(r0+rg)*I_ + c4*4];
    }
    __syncthreads();
    {
      int c4 = tid & 31, rg = tid >> 5;
      int c = c4*4;
      float4 acc = *(const float4*)&bo[c];
      const float* rrow = &big[rg*128];
#pragma unroll 4
      for (int m = 0; m < 128; ++m) {
        float4 wv = *(const float4*)&Wo[(size_t)m*I_ + c];
        float rv = rrow[m];
        acc.x += rv*wv.x; acc.y += rv*wv.y; acc.z += rv*wv.z; acc.w += rv*wv.w;
      }
      *(float4*)&out[(size_t)(r0+rg)*I_ + c] = acc;
    }
  }
}

extern "C" void kernel_launch(void* const* d_in, const int* in_sizes, int n_in,
                              void* d_out, int out_size, void* d_ws, size_t ws_size,
                              hipStream_t stream) {
  (void)in_sizes; (void)n_in; (void)out_size; (void)ws_size;
  // zero barrier area (ws is re-poisoned before every timed launch)
  hipMemsetAsync((char*)d_ws + (size_t)WS_BAR*sizeof(float), 0, 2048, stream);

  const float* a0  = (const float*)d_in[0];   // x
  const float* a1  = (const float*)d_in[1];   // Wc
  const float* a2  = (const float*)d_in[2];   // bc
  const float* a3  = (const float*)d_in[3];   // Wk
  const float* a4  = (const float*)d_in[4];   // bk
  const float* a5  = (const float*)d_in[5];   // Wb
  const float* a6  = (const float*)d_in[6];   // bb
  const float* a7  = (const float*)d_in[7];   // Wg
  const float* a8  = (const float*)d_in[8];   // bg
  const float* a9  = (const float*)d_in[9];   // Ws
  const float* a10 = (const float*)d_in[10];  // bs
  const float* a11 = (const float*)d_in[11];  // Wgam
  const float* a12 = (const float*)d_in[12];  // bgam
  const float* a13 = (const float*)d_in[13];  // We
  const float* a14 = (const float*)d_in[14];  // be
  const float* a15 = (const float*)d_in[15];  // Wa
  const float* a16 = (const float*)d_in[16];  // ba
  const float* a17 = (const float*)d_in[17];  // Wo
  const float* a18 = (const float*)d_in[18];  // bo
  const float* a19 = (const float*)d_in[19];  // memory0
  const float* a20 = (const float*)d_in[20];  // ww0
  const float* a21 = (const float*)d_in[21];  // rw0
  const float* a22 = (const float*)d_in[22];  // read0
  float* aout = (float*)d_out;
  float* aws  = (float*)d_ws;

  void* args[] = { &a0,&a1,&a2,&a3,&a4,&a5,&a6,&a7,&a8,&a9,&a10,&a11,&a12,
                   &a13,&a14,&a15,&a16,&a17,&a18,&a19,&a20,&a21,&a22,&aout,&aws };

  hipError_t err = hipLaunchCooperativeKernel((void*)ntm_kernel, dim3(NB), dim3(NT),
                                              args, 0, stream);
  if (err != hipSuccess) {
    // fallback: plain launch (1 block/CU forced by 155KB LDS -> co-resident)
    ntm_kernel<<<dim3(NB), dim3(NT), 0, stream>>>(
        a0,a1,a2,a3,a4,a5,a6,a7,a8,a9,a10,a11,a12,a13,a14,a15,a16,a17,a18,
        a19,a20,a21,a22,aout,aws);
  }
}

// Round 2
// 1464.635 us; speedup vs baseline: 5.9099x; 5.9099x over previous
//
#include <hip/hip_runtime.h>
#include <math.h>

#define T_ 64
#define B_ 256
#define N_ 256
#define M_ 128
#define H_ 1024
#define I_ 128
#define NB 256
#define NT 512
#define MSTR 132          // mem row stride (floats)
#define EPSF 1e-8f

// ---- packed-weight workspace layout (uint offsets) ----
#define WS_WCR  0                       // [32][1024] uint4 -> 131072 uints (Wc fp16 pairs (j, j+128))
#define WS_W2V  131072                  // [128][512] uint4 -> 262144 uints (W2 fp16 pairs (h, h+512))
#define WS_WSM  (131072 + 262144)       // [12][512]  uints (small-head weights, pairs (h, h+512))

typedef _Float16 h2_t __attribute__((ext_vector_type(2)));

__device__ __forceinline__ float fdot2(unsigned a, unsigned b, float c) {
#if __has_builtin(__builtin_amdgcn_fdot2)
  union { unsigned u; h2_t h; } ua, ub;
  ua.u = a; ub.u = b;
  return __builtin_amdgcn_fdot2(ua.h, ub.h, c, false);
#else
  union { unsigned u; _Float16 h[2]; } ua, ub;
  ua.u = a; ub.u = b;
  return c + (float)ua.h[0] * (float)ub.h[0] + (float)ua.h[1] * (float)ub.h[1];
#endif
}

__device__ __forceinline__ unsigned packh2(float a, float b) {
  union { h2_t h; unsigned u; } v;
  v.h = h2_t{(_Float16)a, (_Float16)b};
  return v.u;
}

__device__ __forceinline__ float wave_rsum(float v) {
#pragma unroll
  for (int o = 32; o > 0; o >>= 1) v += __shfl_xor(v, o, 64);
  return v;
}
__device__ __forceinline__ float wave_rmax(float v) {
#pragma unroll
  for (int o = 32; o > 0; o >>= 1) v = fmaxf(v, __shfl_xor(v, o, 64));
  return v;
}

// ================= pack kernel: fp32 weights -> fp16 pair-packed =================
__global__ void ntm_pack(const float* __restrict__ Wc, const float* __restrict__ Wk,
                         const float* __restrict__ Wb, const float* __restrict__ Wg,
                         const float* __restrict__ Wsf, const float* __restrict__ Wgm,
                         const float* __restrict__ We, const float* __restrict__ Wa,
                         unsigned* __restrict__ wsu)
{
  const int total = 131072 + 262144 + 6144;
  for (int i = blockIdx.x * blockDim.x + threadIdx.x; i < total;
       i += gridDim.x * blockDim.x) {
    if (i < 131072) {
      // WcR: u = k8*4096 + h*4 + jm ; pair j = k8*4+jm over inp=[x(128)|rd(128)]
      int u = i;
      int k8 = u >> 12, rem = u & 4095, h = rem >> 2, jm = rem & 3;
      int j = k8 * 4 + jm;
      wsu[WS_WCR + u] = packh2(Wc[(size_t)j * H_ + h], Wc[(size_t)(j + 128) * H_ + h]);
    } else if (i < 131072 + 262144) {
      // W2v: u = k8*2048 + c*4 + jm ; pair h = (k8*4+jm, +512)
      int u = i - 131072;
      int k8 = u >> 11, rem = u & 2047, c = rem >> 2, jm = rem & 3;
      int h = k8 * 4 + jm;
      float v0, v1;
      if (c < 128)      { v0 = Wk[(size_t)h * M_ + c];             v1 = Wk[(size_t)(h + 512) * M_ + c]; }
      else if (c < 256) { v0 = Wk[(size_t)H_ * M_ + (size_t)h * M_ + (c - 128)];
                          v1 = Wk[(size_t)H_ * M_ + (size_t)(h + 512) * M_ + (c - 128)]; }
      else if (c < 384) { v0 = We[(size_t)h * M_ + (c - 256)];     v1 = We[(size_t)(h + 512) * M_ + (c - 256)]; }
      else              { v0 = Wa[(size_t)h * M_ + (c - 384)];     v1 = Wa[(size_t)(h + 512) * M_ + (c - 384)]; }
      wsu[WS_W2V + u] = packh2(v0, v1);
    } else {
      // Wsm16: d in [0,12), j in [0,512): pair (h=j, h=j+512)
      int u = i - 131072 - 262144;
      int d = u >> 9, j = u & 511;
      float v0, v1;
      if (d < 2)      { v0 = Wb[d * H_ + j];        v1 = Wb[d * H_ + j + 512]; }
      else if (d < 4) { v0 = Wg[(d - 2) * H_ + j];  v1 = Wg[(d - 2) * H_ + j + 512]; }
      else if (d < 6) { v0 = Wgm[(d - 4) * H_ + j]; v1 = Wgm[(d - 4) * H_ + j + 512]; }
      else if (d < 9) { v0 = Wsf[j * 3 + (d - 6)];  v1 = Wsf[(j + 512) * 3 + (d - 6)]; }
      else            { v0 = Wsf[3 * H_ + j * 3 + (d - 9)]; v1 = Wsf[3 * H_ + (j + 512) * 3 + (d - 9)]; }
      wsu[WS_WSM + u] = packh2(v0, v1);
    }
  }
}

// ================= main kernel: one persistent block per batch element =================
__global__ __launch_bounds__(NT)
void ntm_main(const float* __restrict__ x,
              const float* __restrict__ bc,  const float* __restrict__ bk,
              const float* __restrict__ bbv, const float* __restrict__ bg,
              const float* __restrict__ bsf, const float* __restrict__ bgm,
              const float* __restrict__ be,  const float* __restrict__ ba,
              const float* __restrict__ Wo,  const float* __restrict__ bo,
              const float* __restrict__ mem0, const float* __restrict__ ww0,
              const float* __restrict__ rw0,  const float* __restrict__ rd0,
              const unsigned* __restrict__ wsu,
              float* __restrict__ out)
{
  __shared__ __align__(16) float mem[N_ * MSTR];   // 135168 B
  __shared__ __align__(16) float hts[H_];          // 4096
  __shared__ __align__(16) unsigned htp[512];      // 2048  (ht fp16 pairs (h,h+512))
  __shared__ __align__(16) unsigned inpp[128];     // 512   (inp pairs (x_j, rd_j))
  __shared__ __align__(16) float prevw[2 * N_];    // 2048  ww | rw
  __shared__ __align__(16) float mnv[N_];          // 1024
  __shared__ __align__(16) float ksh[2 * M_];      // 1024
  __shared__ __align__(16) float eah[2 * M_];      // 1024  erase | add
  __shared__ __align__(16) float wlog[2 * N_];     // 2048
  __shared__ __align__(16) float wtmp[2 * N_];     // 2048
  __shared__ __align__(16) float red[2 * N_];      // 2048
  __shared__ __align__(16) float red2[2 * N_];     // 2048
  __shared__ __align__(16) float rds[M_];          // 512
  __shared__ __align__(16) float scal[32];         // 128
  __shared__ __align__(16) float bcL[H_];          // 4096
  __shared__ __align__(16) float bkL[256];         // 1024
  __shared__ __align__(16) float beL[128];         // 512
  __shared__ __align__(16) float baL[128];         // 512
  __shared__ __align__(16) float boL[128];         // 512
  __shared__ __align__(16) float sb[16];           // 64

  const int tid = threadIdx.x;
  const int b = blockIdx.x;
  const uint4* WcR4 = (const uint4*)(wsu + WS_WCR);
  const uint4* W2v4 = (const uint4*)(wsu + WS_W2V);
  const uint4* Wsm4 = (const uint4*)(wsu + WS_WSM);
  const uint4* ip4 = (const uint4*)inpp;
  const uint4* hp4 = (const uint4*)htp;

  // ---------- prologue ----------
  for (int i = tid; i < N_ * M_; i += NT)
    mem[(i >> 7) * MSTR + (i & 127)] = mem0[i];
  for (int i = tid; i < H_; i += NT) bcL[i] = bc[i];
  if (tid < 256) bkL[tid] = bk[tid];
  if (tid < 128) { beL[tid] = be[tid]; baL[tid] = ba[tid]; boL[tid] = bo[tid]; rds[tid] = rd0[tid]; }
  if (tid < 12) {
    float v;
    if (tid < 2) v = bbv[tid];
    else if (tid < 4) v = bg[tid - 2];
    else if (tid < 6) v = bgm[tid - 4];
    else v = bsf[tid - 6];
    sb[tid] = v;
  }
  if (tid < 256) { wlog[tid] = ww0[tid]; wlog[256 + tid] = rw0[tid]; }
  __syncthreads();
  if (tid < 256) {
    float s = 0.f;
#pragma unroll 8
    for (int m = 0; m < M_; ++m) { float v = mem[tid * MSTR + m]; s += v * v; }
    mnv[tid] = fmaxf(sqrtf(s), EPSF);
  }
  __syncthreads();
  { // softmax of initial weights (waves 0,1)
    int wv = tid >> 6, ln = tid & 63;
    if (wv < 2) {
      float l0 = wlog[wv * N_ + ln], l1 = wlog[wv * N_ + 64 + ln],
            l2 = wlog[wv * N_ + 128 + ln], l3 = wlog[wv * N_ + 192 + ln];
      float mx = wave_rmax(fmaxf(fmaxf(l0, l1), fmaxf(l2, l3)));
      float e0 = __expf(l0 - mx), e1 = __expf(l1 - mx), e2 = __expf(l2 - mx), e3 = __expf(l3 - mx);
      float sm = wave_rsum(e0 + e1 + e2 + e3);
      wlog[wv * N_ + ln] = e0; wlog[wv * N_ + 64 + ln] = e1;
      wlog[wv * N_ + 128 + ln] = e2; wlog[wv * N_ + 192 + ln] = e3;
      if (ln == 0) scal[30 + wv] = 1.f / sm;
    }
  }
  __syncthreads();
  prevw[tid] = wlog[tid] * scal[30 + (tid >> 8)];
  if (tid < 128) inpp[tid] = packh2(x[(size_t)b * I_ + tid], rds[tid]);
  __syncthreads();

  // ---------- time loop ----------
  for (int t = 0; t < T_; ++t) {
    // phase A: ht = tanh(inp @ Wc + bc); thread j -> h = j, j+512
    {
      const int j = tid;
      float a0 = 0.f, a1 = 0.f;
#pragma unroll 8
      for (int k8 = 0; k8 < 32; ++k8) {
        uint4 wa = WcR4[k8 * 1024 + j];
        uint4 wb = WcR4[k8 * 1024 + 512 + j];
        uint4 ip = ip4[k8];
        a0 = fdot2(wa.x, ip.x, a0); a0 = fdot2(wa.y, ip.y, a0);
        a0 = fdot2(wa.z, ip.z, a0); a0 = fdot2(wa.w, ip.w, a0);
        a1 = fdot2(wb.x, ip.x, a1); a1 = fdot2(wb.y, ip.y, a1);
        a1 = fdot2(wb.z, ip.z, a1); a1 = fdot2(wb.w, ip.w, a1);
      }
      float t0 = tanhf(a0 + bcL[j]);
      float t1 = tanhf(a1 + bcL[j + 512]);
      hts[j] = t0; hts[j + 512] = t1;
      htp[j] = packh2(t0, t1);
    }
    __syncthreads();

    // phase B: proj col j = ht @ W2[:,j]; activations applied in place
    {
      const int j = tid;
      float acc = 0.f;
#pragma unroll 8
      for (int k8 = 0; k8 < 128; ++k8) {
        uint4 wv = W2v4[k8 * 512 + j];
        uint4 hv = hp4[k8];
        acc = fdot2(wv.x, hv.x, acc); acc = fdot2(wv.y, hv.y, acc);
        acc = fdot2(wv.z, hv.z, acc); acc = fdot2(wv.w, hv.w, acc);
      }
      if (j < 256)      ksh[j] = fmaxf(acc + bkL[j], 0.f);
      else if (j < 384) eah[j - 256] = 1.f / (1.f + __expf(-(acc + beL[j - 256])));
      else              eah[j - 256] = 1.f / (1.f + __expf(-(acc + baL[j - 384])));
    }
    __syncthreads();

    // C1: 12 small dots (waves 0-5) + key norms (waves 6-7)
    {
      int wv = tid >> 6, ln = tid & 63;
      if (wv < 6) {
        for (int dd = 0; dd < 2; ++dd) {
          int d = wv * 2 + dd;
          uint4 wA = Wsm4[d * 128 + ln * 2];
          uint4 wB = Wsm4[d * 128 + ln * 2 + 1];
          uint4 hA = hp4[ln * 2];
          uint4 hB = hp4[ln * 2 + 1];
          float s = 0.f;
          s = fdot2(wA.x, hA.x, s); s = fdot2(wA.y, hA.y, s);
          s = fdot2(wA.z, hA.z, s); s = fdot2(wA.w, hA.w, s);
          s = fdot2(wB.x, hB.x, s); s = fdot2(wB.y, hB.y, s);
          s = fdot2(wB.z, hB.z, s); s = fdot2(wB.w, hB.w, s);
          s = wave_rsum(s);
          if (ln == 0) scal[d] = s;
        }
      } else if (wv < 8) {
        int h = wv - 6;
        float v0 = ksh[h * 128 + ln], v1 = ksh[h * 128 + 64 + ln];
        float s = wave_rsum(v0 * v0 + v1 * v1);
        if (ln == 0) scal[12 + h] = fmaxf(sqrtf(s), EPSF);
      }
    }
    __syncthreads();

    // C2: scalar finalize
    if (tid == 0) {
      for (int h = 0; h < 2; ++h) {
        float rb = scal[h] + sb[h];
        scal[16 + h] = (rb > 20.f) ? rb : log1pf(__expf(rb));        // softplus beta
        scal[18 + h] = 1.f / (1.f + __expf(-(scal[2 + h] + sb[2 + h])));  // g
        scal[20 + h] = fmaxf(scal[4 + h] + sb[4 + h], 0.f) + 1.f;    // gamma
        float s0 = scal[6 + 3 * h] + sb[6 + 3 * h];
        float s1 = scal[7 + 3 * h] + sb[7 + 3 * h];
        float s2 = scal[8 + 3 * h] + sb[8 + 3 * h];
        float mx = fmaxf(s0, fmaxf(s1, s2));
        float e0 = __expf(s0 - mx), e1 = __expf(s1 - mx), e2 = __expf(s2 - mx);
        float inv = 1.f / (e0 + e1 + e2);
        scal[22 + 3 * h] = e0 * inv; scal[23 + 3 * h] = e1 * inv; scal[24 + 3 * h] = e2 * inv;
      }
    }
    __syncthreads();

    // C3: cosine logits (8 waves: head = wv&1, 64 rows each)
    {
      int wv = tid >> 6, ln = tid & 63;
      int h = wv & 1, n = (wv >> 1) * 64 + ln;
      const float beta = scal[16 + h], kn = scal[12 + h];
      const float4* kp = (const float4*)&ksh[h * 128];
      const float* mrow = &mem[n * MSTR];
      float dot = 0.f;
#pragma unroll 8
      for (int m4 = 0; m4 < 32; ++m4) {
        float4 kv = kp[m4];
        float4 mv = *(const float4*)&mrow[m4 * 4];
        dot += kv.x * mv.x + kv.y * mv.y + kv.z * mv.z + kv.w * mv.w;
      }
      wlog[h * N_ + n] = beta * (dot / (kn * mnv[n]));
    }
    __syncthreads();

    // C4: content softmax (waves 0,1)
    {
      int wv = tid >> 6, ln = tid & 63;
      if (wv < 2) {
        float l0 = wlog[wv * N_ + ln], l1 = wlog[wv * N_ + 64 + ln],
              l2 = wlog[wv * N_ + 128 + ln], l3 = wlog[wv * N_ + 192 + ln];
        float mx = wave_rmax(fmaxf(fmaxf(l0, l1), fmaxf(l2, l3)));
        float e0 = __expf(l0 - mx), e1 = __expf(l1 - mx), e2 = __expf(l2 - mx), e3 = __expf(l3 - mx);
        float sm = wave_rsum(e0 + e1 + e2 + e3);
        wlog[wv * N_ + ln] = e0; wlog[wv * N_ + 64 + ln] = e1;
        wlog[wv * N_ + 128 + ln] = e2; wlog[wv * N_ + 192 + ln] = e3;
        if (ln == 0) scal[30 + wv] = 1.f / sm;
      }
    }
    __syncthreads();

    // C5: interpolate with previous weights
    {
      int h = tid >> 8;
      float g = scal[18 + h];
      wtmp[tid] = g * wlog[tid] * scal[30 + h] + (1.f - g) * prevw[tid];
    }
    __syncthreads();

    // C6: circular shift + sharpen
    {
      int h = tid >> 8, n = tid & 255;
      float v = scal[22 + 3 * h] * wtmp[h * N_ + ((n + 255) & 255)]
              + scal[23 + 3 * h] * wtmp[h * N_ + n]
              + scal[24 + 3 * h] * wtmp[h * N_ + ((n + 1) & 255)];
      wlog[tid] = __powf(v, scal[20 + h]);
    }
    __syncthreads();

    // C7: normalization sums
    {
      int wv = tid >> 6, ln = tid & 63;
      if (wv < 2) {
        float s = wlog[wv * N_ + ln] + wlog[wv * N_ + 64 + ln]
                + wlog[wv * N_ + 128 + ln] + wlog[wv * N_ + 192 + ln];
        s = wave_rsum(s);
        if (ln == 0) scal[14 + wv] = 1.f / s;
      }
    }
    __syncthreads();

    // C8: final weights
    prevw[tid] = wlog[tid] * scal[14 + (tid >> 8)];
    __syncthreads();

    // C9: memory update + row-norm partials
    {
      int n = tid & 255, half = tid >> 8;
      float wwn = prevw[n];
      float* mrow = &mem[n * MSTR + half * 64];
      const float4* ep = (const float4*)&eah[half * 64];
      const float4* ap = (const float4*)&eah[128 + half * 64];
      float sq = 0.f;
#pragma unroll 4
      for (int m4 = 0; m4 < 16; ++m4) {
        float4 mv = *(float4*)&mrow[m4 * 4];
        float4 ev = ep[m4], av = ap[m4];
        mv.x = mv.x * (1.f - wwn * ev.x) + wwn * av.x;
        mv.y = mv.y * (1.f - wwn * ev.y) + wwn * av.y;
        mv.z = mv.z * (1.f - wwn * ev.z) + wwn * av.z;
        mv.w = mv.w * (1.f - wwn * ev.w) + wwn * av.w;
        sq += mv.x * mv.x + mv.y * mv.y + mv.z * mv.z + mv.w * mv.w;
        *(float4*)&mrow[m4 * 4] = mv;
      }
      red[half * N_ + n] = sq;
    }
    __syncthreads();

    // C10: row norms + rd partials
    if (tid < 256) mnv[tid] = fmaxf(sqrtf(red[tid] + red[N_ + tid]), EPSF);
    {
      int m = tid & 127, g = tid >> 7;
      float acc = 0.f;
      const float* base = &mem[(g * 64) * MSTR + m];
#pragma unroll 4
      for (int i = 0; i < 64; ++i)
        acc += prevw[N_ + g * 64 + i] * base[i * MSTR];
      red2[g * 128 + m] = acc;
    }
    __syncthreads();

    // C11: rd final
    if (tid < 128)
      rds[tid] = red2[tid] + red2[128 + tid] + red2[256 + tid] + red2[384 + tid];
    __syncthreads();

    // C12: out = rd @ Wo partials (thread = (c, K-quarter))
    {
      int c = tid & 127, q = tid >> 7;
      int m0 = q * 32;
      float acc = 0.f;
#pragma unroll 8
      for (int mm = 0; mm < 32; ++mm)
        acc += rds[m0 + mm] * Wo[(size_t)(m0 + mm) * I_ + c];
      red[q * 128 + c] = acc;
    }
    __syncthreads();

    // C13: out write + next-step input pack
    if (tid < 128) {
      float v = red[tid] + red[128 + tid] + red[256 + tid] + red[384 + tid] + boL[tid];
      out[((size_t)t * B_ + b) * I_ + tid] = v;
      if (t < T_ - 1)
        inpp[tid] = packh2(x[((size_t)(t + 1) * B_ + b) * I_ + tid], rds[tid]);
    }
    __syncthreads();
  }
}

extern "C" void kernel_launch(void* const* d_in, const int* in_sizes, int n_in,
                              void* d_out, int out_size, void* d_ws, size_t ws_size,
                              hipStream_t stream) {
  (void)in_sizes; (void)n_in; (void)out_size; (void)ws_size;

  const float* x    = (const float*)d_in[0];
  const float* Wc   = (const float*)d_in[1];
  const float* bc   = (const float*)d_in[2];
  const float* Wk   = (const float*)d_in[3];
  const float* bk   = (const float*)d_in[4];
  const float* Wb   = (const float*)d_in[5];
  const float* bbv  = (const float*)d_in[6];
  const float* Wg   = (const float*)d_in[7];
  const float* bg   = (const float*)d_in[8];
  const float* Wsf  = (const float*)d_in[9];
  const float* bsf  = (const float*)d_in[10];
  const float* Wgm  = (const float*)d_in[11];
  const float* bgm  = (const float*)d_in[12];
  const float* We   = (const float*)d_in[13];
  const float* be   = (const float*)d_in[14];
  const float* Wa   = (const float*)d_in[15];
  const float* ba   = (const float*)d_in[16];
  const float* Wo   = (const float*)d_in[17];
  const float* bo   = (const float*)d_in[18];
  const float* mem0 = (const float*)d_in[19];
  const float* ww0  = (const float*)d_in[20];
  const float* rw0  = (const float*)d_in[21];
  const float* rd0  = (const float*)d_in[22];
  float* out = (float*)d_out;
  unsigned* wsu = (unsigned*)d_ws;

  ntm_pack<<<dim3(512), dim3(256), 0, stream>>>(Wc, Wk, Wb, Wg, Wsf, Wgm, We, Wa, wsu);
  ntm_main<<<dim3(NB), dim3(NT), 0, stream>>>(x, bc, bk, bbv, bg, bsf, bgm, be, ba,
                                              Wo, bo, mem0, ww0, rw0, rd0, wsu, out);
}